// Round 9
// baseline (107.438 us; speedup 1.0000x reference)
//
#include <hip/hip_runtime.h>
#include <hip/hip_bf16.h>

#define B_DIM 16
#define KQ    2048
#define W_DIM 2048
#define D_DIM 128
#define QBLK  64
#define KVB   32
#define NT    (W_DIM / KVB)   // 64
#define TILEB 24576           // bytes per (b,t) ws tile == per LDS buffer
#define TILEU 12288           // u16 per tile

typedef float f4 __attribute__((ext_vector_type(4)));
typedef float f32x16 __attribute__((ext_vector_type(16)));
typedef __bf16 bf16x8 __attribute__((ext_vector_type(8)));
typedef unsigned short u16x4 __attribute__((ext_vector_type(4)));
typedef unsigned short u16x8 __attribute__((ext_vector_type(8)));

static __device__ __forceinline__ unsigned short f2bf(float x) {
  __bf16 h = (__bf16)x;
  return __builtin_bit_cast(unsigned short, h);
}

// ws tile layout per (b,t), byte-identical to one LDS buffer:
//   K1 [0,8192):    32 k-rows x 256B; 16B chunk c stored at c' = c ^ (k&7)
//   K2 [8192,16384): same
//   V^T [16384,24576): 128 d-rows x 64B; logical chunk h=2ks+hi stored at
//       h' = h ^ ((d>>1)&3); slot j of chunk (ks,hi) holds V[k=16ks+4hi+(j&3)+8(j>>2)][d]
__global__ __launch_bounds__(256, 2)
void prepass(const float* __restrict__ K1g, const float* __restrict__ K2g,
             const float* __restrict__ Vg, unsigned short* __restrict__ ws)
{
  __shared__ unsigned short lv[KVB][132];
  const int tid = threadIdx.x;
  const int bt  = blockIdx.x;               // b*NT + t
  const size_t gsrc = (size_t)bt * KVB * D_DIM;
  unsigned short* wt = ws + (size_t)bt * TILEU;

#pragma unroll
  for (int uu = 0; uu < 2; ++uu) {
    const int unit = uu * 256 + tid;
    const int k = unit >> 4, c = unit & 15;
    const float* s1 = K1g + gsrc + k * D_DIM + c * 8;
    const float* s2 = K2g + gsrc + k * D_DIM + c * 8;
    f4 a0 = *(const f4*)s1, a1 = *(const f4*)(s1 + 4);
    f4 b0 = *(const f4*)s2, b1 = *(const f4*)(s2 + 4);
    u16x8 o1 = { f2bf(a0[0]), f2bf(a0[1]), f2bf(a0[2]), f2bf(a0[3]),
                 f2bf(a1[0]), f2bf(a1[1]), f2bf(a1[2]), f2bf(a1[3]) };
    u16x8 o2 = { f2bf(b0[0]), f2bf(b0[1]), f2bf(b0[2]), f2bf(b0[3]),
                 f2bf(b1[0]), f2bf(b1[1]), f2bf(b1[2]), f2bf(b1[3]) };
    const int cp = c ^ (k & 7);
    *(u16x8*)(wt + k * 128 + cp * 8)        = o1;
    *(u16x8*)(wt + 4096 + k * 128 + cp * 8) = o2;
  }

#pragma unroll
  for (int uu = 0; uu < 4; ++uu) {
    const int fi = uu * 256 + tid;
    const int k = fi >> 5, d4 = (fi & 31) * 4;
    f4 v = *(const f4*)(Vg + gsrc + k * D_DIM + d4);
    *(u16x4*)&lv[k][d4] = (u16x4){ f2bf(v[0]), f2bf(v[1]), f2bf(v[2]), f2bf(v[3]) };
  }
  __syncthreads();

#pragma unroll
  for (int uu = 0; uu < 2; ++uu) {
    const int unit = uu * 256 + tid;
    const int d = unit >> 2, hp = unit & 3;
    const int h = hp ^ ((d >> 1) & 3);
    const int ks = h >> 1, hi = h & 1;
    u16x8 ov;
#pragma unroll
    for (int j = 0; j < 8; ++j) {
      const int k = 16 * ks + 4 * hi + (j & 3) + 8 * (j >> 2);
      ov[j] = lv[k][d];
    }
    *(u16x8*)(wt + 8192 + d * 32 + hp * 8) = ov;
  }
}

// ---------------- main: 32x32 swapped-operand differential attention ----------------
// Triple-buffered LDS + counted vmcnt(6): loads for tile t+1 retire at the
// iter-t barrier; tile t+2's 6 loads stay in flight across it (T3/T4).
__global__ __launch_bounds__(256, 2)
void diffattn(const float* __restrict__ Q1g, const float* __restrict__ Q2g,
              const unsigned short* __restrict__ ws,
              const float* __restrict__ lamp, float* __restrict__ Og)
{
  __shared__ char smem[3 * TILEB];   // 72KB; epilogue reuses [0,32768)

  const int tid  = threadIdx.x;
  const int wv   = tid >> 6;     // 0..3
  const int lane = tid & 63;
  const int hi   = lane >> 5;
  const int ln   = lane & 31;
  const int s    = wv & 1;       // stream
  const int qh   = wv >> 1;      // q chunk (32 rows)

  // XCD-aware bijective swizzle: 512 = 8 XCDs x 64
  const int wg  = blockIdx.x;
  const int swz = (wg & 7) * 64 + (wg >> 3);
  const int qt  = swz & 31;
  const int b   = swz >> 5;
  const int q0  = qt * QBLK;

  const float qscale = 0.08838834764831845f * 1.4426950408889634f; // 1/sqrt(128)*log2(e)

  // ---- Q fragments (B-operand): lane = q-col ln, d-slots hi*8+j+16*step
  const float* Qs = s ? Q2g : Q1g;
  bf16x8 qf[8];
  {
    const float* qp = Qs + ((size_t)b * KQ + q0 + qh * 32 + ln) * D_DIM + hi * 8;
#pragma unroll
    for (int st = 0; st < 8; ++st) {
      f4 lo = *(const f4*)(qp + st * 16);
      f4 h4 = *(const f4*)(qp + st * 16 + 4);
      bf16x8 tq;
#pragma unroll
      for (int j = 0; j < 4; ++j) {
        tq[j]     = (__bf16)(lo[j] * qscale);
        tq[4 + j] = (__bf16)(h4[j] * qscale);
      }
      qf[st] = tq;
    }
  }

  f32x16 o[4];
#pragma unroll
  for (int db = 0; db < 4; ++db)
#pragma unroll
    for (int i = 0; i < 16; ++i) o[db][i] = 0.f;

  float lsp[4] = {0.f, 0.f, 0.f, 0.f};   // split row-sum partials

  // ---- addresses ----
  const unsigned short* wsb = ws + (size_t)b * NT * TILEU;
  int kaddr[8];
#pragma unroll
  for (int st = 0; st < 8; ++st)
    kaddr[st] = s * 8192 + ln * 256 + (((2 * st + hi) ^ (ln & 7)) << 4);
  const int vb0 = 16384 + ln * 64;
  int vswz[2];
#pragma unroll
  for (int ks = 0; ks < 2; ++ks) vswz[ks] = (((2 * ks + hi) ^ ((ln >> 1) & 3)) << 4);

  auto STAGE = [&](int t, char* dB) {
    const unsigned short* sp0 = wsb + (size_t)t * TILEU + lane * 8;
#pragma unroll
    for (int i = 0; i < 6; ++i) {
      const int ch = wv * 6 + i;
      __builtin_amdgcn_global_load_lds(
          (const __attribute__((address_space(1))) void*)(sp0 + ch * 512),
          (__attribute__((address_space(3))) void*)(dB + ch * 1024), 16, 0, 0);
    }
  };

  char* pA = smem;
  char* pB = smem + TILEB;
  char* pC = smem + 2 * TILEB;

  STAGE(0, pA);
  STAGE(1, pB);
  __builtin_amdgcn_sched_barrier(0);
  asm volatile("s_waitcnt vmcnt(6)" ::: "memory");   // tile 0 resident
  __builtin_amdgcn_s_barrier();
  __builtin_amdgcn_sched_barrier(0);

#pragma unroll 1
  for (int t = 0; t < NT; ++t) {
    // issue loads for t+2 first (T3 ordering); clamped dup at tail is benign
    const int t2 = (t + 2 < NT) ? t + 2 : NT - 1;
    STAGE(t2, pC);

    // ---- QK^T swapped: S[k-row][q=ln]; split accumulators (dep chain 4) ----
    f32x16 s0, s1;
#pragma unroll
    for (int i = 0; i < 16; ++i) { s0[i] = 0.f; s1[i] = 0.f; }
    __builtin_amdgcn_s_setprio(1);
#pragma unroll
    for (int st = 0; st < 4; ++st) {
      const bf16x8 a0 = *(const bf16x8*)(pA + kaddr[st]);
      const bf16x8 a1 = *(const bf16x8*)(pA + kaddr[st + 4]);
      s0 = __builtin_amdgcn_mfma_f32_32x32x16_bf16(a0, qf[st], s0, 0, 0, 0);
      s1 = __builtin_amdgcn_mfma_f32_32x32x16_bf16(a1, qf[st + 4], s1, 0, 0, 0);
    }
    __builtin_amdgcn_s_setprio(0);

    // ---- unnormalized exp2 (no max); P packed into PV A-fragments ----
    bf16x8 pa[2];
#pragma unroll
    for (int ks = 0; ks < 2; ++ks) {
      bf16x8 pv;
#pragma unroll
      for (int j = 0; j < 8; ++j) {
        const float p = exp2f(s0[8 * ks + j] + s1[8 * ks + j]);
        lsp[j & 3] += p;
        pv[j] = (__bf16)p;    // slot j <-> k = 16ks + 4hi + (j&3) + 8(j>>2)
      }
      pa[ks] = pv;
    }

    // ---- PV: O[q][d] ----
    __builtin_amdgcn_s_setprio(1);
#pragma unroll
    for (int db = 0; db < 4; ++db) {
#pragma unroll
      for (int ks = 0; ks < 2; ++ks) {
        const bf16x8 vb = *(const bf16x8*)(pA + vb0 + db * 2048 + vswz[ks]);
        o[db] = __builtin_amdgcn_mfma_f32_32x32x16_bf16(pa[ks], vb, o[db], 0, 0, 0);
      }
    }
    __builtin_amdgcn_s_setprio(0);

    // ---- counted-vmcnt barrier: only t+1's loads must have retired ----
    __builtin_amdgcn_sched_barrier(0);
    asm volatile("s_waitcnt vmcnt(6)" ::: "memory");
    __builtin_amdgcn_s_barrier();
    __builtin_amdgcn_sched_barrier(0);

    char* tmp = pA; pA = pB; pB = pC; pC = tmp;
  }

  // ---- epilogue: reduce l, combine streams via LDS ----
  const float lam = 1.f / (1.f + __expf(-lamp[0]));
  float ls = (lsp[0] + lsp[1]) + (lsp[2] + lsp[3]);
  const float lt  = ls + __shfl_xor(ls, 32);
  const float fac = s ? lam : 1.f;
  float wq[16];
#pragma unroll
  for (int r = 0; r < 16; ++r)
    wq[r] = fac / __shfl(lt, (r & 3) + 8 * (r >> 2) + 4 * hi);

  if (s == 1) {
#pragma unroll
    for (int db = 0; db < 4; ++db)
#pragma unroll
      for (int r = 0; r < 16; ++r) {
        const int q = qh * 32 + (r & 3) + 8 * (r >> 2) + 4 * hi;
        *(float*)(smem + q * 512 + (db * 32 + ln) * 4) = o[db][r] * wq[r];
      }
  }
  __syncthreads();
  if (s == 0) {
    float* op = Og + ((size_t)b * KQ + q0) * D_DIM;
#pragma unroll
    for (int db = 0; db < 4; ++db)
#pragma unroll
      for (int r = 0; r < 16; ++r) {
        const int q = qh * 32 + (r & 3) + 8 * (r >> 2) + 4 * hi;
        const float o2v = *(const float*)(smem + q * 512 + (db * 32 + ln) * 4);
        op[q * D_DIM + db * 32 + ln] = o[db][r] * wq[r] - o2v;
      }
  }
}

extern "C" void kernel_launch(void* const* d_in, const int* in_sizes, int n_in,
                              void* d_out, int out_size, void* d_ws, size_t ws_size,
                              hipStream_t stream) {
  const float* Q1 = (const float*)d_in[0];
  const float* Q2 = (const float*)d_in[1];
  const float* K1 = (const float*)d_in[2];
  const float* K2 = (const float*)d_in[3];
  const float* V  = (const float*)d_in[4];
  const float* lm = (const float*)d_in[5];
  float* O = (float*)d_out;

  unsigned short* wsp = (unsigned short*)d_ws;   // 24 MB

  prepass<<<dim3(B_DIM * NT), dim3(256), 0, stream>>>(K1, K2, V, wsp);
  diffattn<<<dim3(B_DIM * (KQ / QBLK)), dim3(256), 0, stream>>>(Q1, Q2, wsp, lm, O);
}

// Round 10
// 96.140 us; speedup vs baseline: 1.1175x; 1.1175x over previous
//
#include <hip/hip_runtime.h>
#include <hip/hip_bf16.h>

#define B_DIM 16
#define KQ    2048
#define W_DIM 2048
#define D_DIM 128
#define QBLK  64
#define KVB   32
#define NT    (W_DIM / KVB)   // 64
#define TILEB 24576           // bytes per (b,t) ws tile == per LDS buffer
#define TILEU 12288           // u16 per tile

typedef float f4 __attribute__((ext_vector_type(4)));
typedef float f32x16 __attribute__((ext_vector_type(16)));
typedef __bf16 bf16x8 __attribute__((ext_vector_type(8)));
typedef unsigned short u16x4 __attribute__((ext_vector_type(4)));
typedef unsigned short u16x8 __attribute__((ext_vector_type(8)));

static __device__ __forceinline__ unsigned short f2bf(float x) {
  __bf16 h = (__bf16)x;
  return __builtin_bit_cast(unsigned short, h);
}

// ws tile layout per (b,t), byte-identical to one LDS buffer:
//   K1 [0,8192):    32 k-rows x 256B; 16B chunk c stored at c' = c ^ (k&7)
//   K2 [8192,16384): same
//   V^T [16384,24576): 128 d-rows x 64B; logical chunk h=2ks+hi stored at
//       h' = h ^ ((d>>1)&3); slot j of chunk (ks,hi) holds V[k=16ks+4hi+(j&3)+8(j>>2)][d]
__global__ __launch_bounds__(256, 2)
void prepass(const float* __restrict__ K1g, const float* __restrict__ K2g,
             const float* __restrict__ Vg, unsigned short* __restrict__ ws)
{
  __shared__ unsigned short lv[KVB][132];
  const int tid = threadIdx.x;
  const int bt  = blockIdx.x;               // b*NT + t
  const size_t gsrc = (size_t)bt * KVB * D_DIM;
  unsigned short* wt = ws + (size_t)bt * TILEU;

#pragma unroll
  for (int uu = 0; uu < 2; ++uu) {
    const int unit = uu * 256 + tid;
    const int k = unit >> 4, c = unit & 15;
    const float* s1 = K1g + gsrc + k * D_DIM + c * 8;
    const float* s2 = K2g + gsrc + k * D_DIM + c * 8;
    f4 a0 = *(const f4*)s1, a1 = *(const f4*)(s1 + 4);
    f4 b0 = *(const f4*)s2, b1 = *(const f4*)(s2 + 4);
    u16x8 o1 = { f2bf(a0[0]), f2bf(a0[1]), f2bf(a0[2]), f2bf(a0[3]),
                 f2bf(a1[0]), f2bf(a1[1]), f2bf(a1[2]), f2bf(a1[3]) };
    u16x8 o2 = { f2bf(b0[0]), f2bf(b0[1]), f2bf(b0[2]), f2bf(b0[3]),
                 f2bf(b1[0]), f2bf(b1[1]), f2bf(b1[2]), f2bf(b1[3]) };
    const int cp = c ^ (k & 7);
    *(u16x8*)(wt + k * 128 + cp * 8)        = o1;
    *(u16x8*)(wt + 4096 + k * 128 + cp * 8) = o2;
  }

#pragma unroll
  for (int uu = 0; uu < 4; ++uu) {
    const int fi = uu * 256 + tid;
    const int k = fi >> 5, d4 = (fi & 31) * 4;
    f4 v = *(const f4*)(Vg + gsrc + k * D_DIM + d4);
    *(u16x4*)&lv[k][d4] = (u16x4){ f2bf(v[0]), f2bf(v[1]), f2bf(v[2]), f2bf(v[3]) };
  }
  __syncthreads();

#pragma unroll
  for (int uu = 0; uu < 2; ++uu) {
    const int unit = uu * 256 + tid;
    const int d = unit >> 2, hp = unit & 3;
    const int h = hp ^ ((d >> 1) & 3);
    const int ks = h >> 1, hi = h & 1;
    u16x8 ov;
#pragma unroll
    for (int j = 0; j < 8; ++j) {
      const int k = 16 * ks + 4 * hi + (j & 3) + 8 * (j >> 2);
      ov[j] = lv[k][d];
    }
    *(u16x8*)(wt + 8192 + d * 32 + hp * 8) = ov;
  }
}

// ---------------- main: 32x32 swapped-operand differential attention ----------------
// T15 pipeline: iter t = [QK(t) + PV(t-1)] one MFMA burst -> exp(t) -> V(t)->regs.
// P and V fragments live in registers across the barrier (single-state,
// use-before-overwrite, static indices).
__global__ __launch_bounds__(256, 2)
void diffattn(const float* __restrict__ Q1g, const float* __restrict__ Q2g,
              const unsigned short* __restrict__ ws,
              const float* __restrict__ lamp, float* __restrict__ Og)
{
  __shared__ char smem[3 * TILEB];   // 72KB; epilogue reuses [0,32768)

  const int tid  = threadIdx.x;
  const int wv   = tid >> 6;     // 0..3
  const int lane = tid & 63;
  const int hi   = lane >> 5;
  const int ln   = lane & 31;
  const int s    = wv & 1;       // stream
  const int qh   = wv >> 1;      // q chunk (32 rows)

  // XCD-aware bijective swizzle: 512 = 8 XCDs x 64
  const int wg  = blockIdx.x;
  const int swz = (wg & 7) * 64 + (wg >> 3);
  const int qt  = swz & 31;
  const int b   = swz >> 5;
  const int q0  = qt * QBLK;

  const float qscale = 0.08838834764831845f * 1.4426950408889634f; // 1/sqrt(128)*log2(e)

  // ---- Q fragments (B-operand): lane = q-col ln, d-slots hi*8+j+16*step
  const float* Qs = s ? Q2g : Q1g;
  bf16x8 qf[8];
  {
    const float* qp = Qs + ((size_t)b * KQ + q0 + qh * 32 + ln) * D_DIM + hi * 8;
#pragma unroll
    for (int st = 0; st < 8; ++st) {
      f4 lo = *(const f4*)(qp + st * 16);
      f4 h4 = *(const f4*)(qp + st * 16 + 4);
      bf16x8 tq;
#pragma unroll
      for (int j = 0; j < 4; ++j) {
        tq[j]     = (__bf16)(lo[j] * qscale);
        tq[4 + j] = (__bf16)(h4[j] * qscale);
      }
      qf[st] = tq;
    }
  }

  f32x16 o[4];
#pragma unroll
  for (int db = 0; db < 4; ++db)
#pragma unroll
    for (int i = 0; i < 16; ++i) o[db][i] = 0.f;

  float lsp[4] = {0.f, 0.f, 0.f, 0.f};   // split row-sum partials

  // ---- addresses ----
  const unsigned short* wsb = ws + (size_t)b * NT * TILEU;
  int kaddr[8];
#pragma unroll
  for (int st = 0; st < 8; ++st)
    kaddr[st] = s * 8192 + ln * 256 + (((2 * st + hi) ^ (ln & 7)) << 4);
  const int vb0 = 16384 + ln * 64;
  int vswz[2];
#pragma unroll
  for (int ks = 0; ks < 2; ++ks) vswz[ks] = (((2 * ks + hi) ^ ((ln >> 1) & 3)) << 4);

  auto STAGE = [&](int t, char* dB) {
    const unsigned short* sp0 = wsb + (size_t)t * TILEU + lane * 8;
#pragma unroll
    for (int i = 0; i < 6; ++i) {
      const int ch = wv * 6 + i;
      __builtin_amdgcn_global_load_lds(
          (const __attribute__((address_space(1))) void*)(sp0 + ch * 512),
          (__attribute__((address_space(3))) void*)(dB + ch * 1024), 16, 0, 0);
    }
  };

  char* pA = smem;
  char* pB = smem + TILEB;
  char* pC = smem + 2 * TILEB;

  STAGE(0, pA);
  STAGE(1, pB);
  __builtin_amdgcn_sched_barrier(0);
  asm volatile("s_waitcnt vmcnt(6)" ::: "memory");   // tile 0 resident
  __builtin_amdgcn_s_barrier();
  __builtin_amdgcn_sched_barrier(0);

  bf16x8 paP[2];   // P fragments of tile t-1 (registers)
  bf16x8 vvP[8];   // V fragments of tile t-1 (registers), idx = db*2+ks

#pragma unroll 1
  for (int t = 0; t < NT; ++t) {
    const int t2 = (t + 2 < NT) ? t + 2 : NT - 1;   // dup at tail keeps vmcnt counting valid
    STAGE(t2, pC);

    // ---- one contiguous MFMA burst: QK(t) + PV(t-1) ----
    f32x16 s0, s1;
#pragma unroll
    for (int i = 0; i < 16; ++i) { s0[i] = 0.f; s1[i] = 0.f; }
    __builtin_amdgcn_s_setprio(1);
#pragma unroll
    for (int st = 0; st < 4; ++st) {
      const bf16x8 a0 = *(const bf16x8*)(pA + kaddr[st]);
      const bf16x8 a1 = *(const bf16x8*)(pA + kaddr[st + 4]);
      s0 = __builtin_amdgcn_mfma_f32_32x32x16_bf16(a0, qf[st], s0, 0, 0, 0);
      s1 = __builtin_amdgcn_mfma_f32_32x32x16_bf16(a1, qf[st + 4], s1, 0, 0, 0);
    }
    if (t) {
#pragma unroll
      for (int db = 0; db < 4; ++db)
#pragma unroll
        for (int ks = 0; ks < 2; ++ks)
          o[db] = __builtin_amdgcn_mfma_f32_32x32x16_bf16(paP[ks], vvP[db * 2 + ks], o[db], 0, 0, 0);
    }
    __builtin_amdgcn_s_setprio(0);

    // ---- unnormalized exp2 via raw v_exp_f32; P packed into A-fragments ----
#pragma unroll
    for (int ks = 0; ks < 2; ++ks) {
      bf16x8 pv;
#pragma unroll
      for (int j = 0; j < 8; ++j) {
        const float p = __builtin_amdgcn_exp2f(s0[8 * ks + j] + s1[8 * ks + j]);
        lsp[j & 3] += p;
        pv[j] = (__bf16)p;    // slot j <-> k = 16ks + 4hi + (j&3) + 8(j>>2)
      }
      paP[ks] = pv;           // overwrite AFTER PV consumed previous value
    }

    // ---- V fragments of tile t -> registers (consumed next iter) ----
#pragma unroll
    for (int db = 0; db < 4; ++db)
#pragma unroll
      for (int ks = 0; ks < 2; ++ks)
        vvP[db * 2 + ks] = *(const bf16x8*)(pA + vb0 + db * 2048 + vswz[ks]);

    // lgkmcnt(0): V reads must land before any wave's next-iter staging
    // can overwrite this slot; vmcnt(6): tile t+1 resident, t+2 in flight.
    __builtin_amdgcn_sched_barrier(0);
    asm volatile("s_waitcnt vmcnt(6) lgkmcnt(0)" ::: "memory");
    __builtin_amdgcn_s_barrier();
    __builtin_amdgcn_sched_barrier(0);

    char* tmp = pA; pA = pB; pB = pC; pC = tmp;
  }

  // drain tail dup-stages before epilogue LDS reuse / kernel end
  asm volatile("s_waitcnt vmcnt(0)" ::: "memory");

  // ---- final PV for tile NT-1 ----
#pragma unroll
  for (int db = 0; db < 4; ++db)
#pragma unroll
    for (int ks = 0; ks < 2; ++ks)
      o[db] = __builtin_amdgcn_mfma_f32_32x32x16_bf16(paP[ks], vvP[db * 2 + ks], o[db], 0, 0, 0);

  // ---- epilogue: reduce l, combine streams via LDS ----
  const float lam = 1.f / (1.f + __expf(-lamp[0]));
  float ls = (lsp[0] + lsp[1]) + (lsp[2] + lsp[3]);
  const float lt  = ls + __shfl_xor(ls, 32);
  const float fac = s ? lam : 1.f;
  float wq[16];
#pragma unroll
  for (int r = 0; r < 16; ++r)
    wq[r] = fac / __shfl(lt, (r & 3) + 8 * (r >> 2) + 4 * hi);

  if (s == 1) {
#pragma unroll
    for (int db = 0; db < 4; ++db)
#pragma unroll
      for (int r = 0; r < 16; ++r) {
        const int q = qh * 32 + (r & 3) + 8 * (r >> 2) + 4 * hi;
        *(float*)(smem + q * 512 + (db * 32 + ln) * 4) = o[db][r] * wq[r];
      }
  }
  __syncthreads();
  if (s == 0) {
    float* op = Og + ((size_t)b * KQ + q0) * D_DIM;
#pragma unroll
    for (int db = 0; db < 4; ++db)
#pragma unroll
      for (int r = 0; r < 16; ++r) {
        const int q = qh * 32 + (r & 3) + 8 * (r >> 2) + 4 * hi;
        const float o2v = *(const float*)(smem + q * 512 + (db * 32 + ln) * 4);
        op[q * D_DIM + db * 32 + ln] = o[db][r] * wq[r] - o2v;
      }
  }
}

extern "C" void kernel_launch(void* const* d_in, const int* in_sizes, int n_in,
                              void* d_out, int out_size, void* d_ws, size_t ws_size,
                              hipStream_t stream) {
  const float* Q1 = (const float*)d_in[0];
  const float* Q2 = (const float*)d_in[1];
  const float* K1 = (const float*)d_in[2];
  const float* K2 = (const float*)d_in[3];
  const float* V  = (const float*)d_in[4];
  const float* lm = (const float*)d_in[5];
  float* O = (float*)d_out;

  unsigned short* wsp = (unsigned short*)d_ws;   // 24 MB

  prepass<<<dim3(B_DIM * NT), dim3(256), 0, stream>>>(K1, K2, V, wsp);
  diffattn<<<dim3(B_DIM * (KQ / QBLK)), dim3(256), 0, stream>>>(Q1, Q2, wsp, lm, O);
}